// Round 3
// baseline (362.716 us; speedup 1.0000x reference)
//
#include <hip/hip_runtime.h>
#include <hip/hip_bf16.h>

typedef short bf16x8 __attribute__((ext_vector_type(8)));
typedef float f32x4 __attribute__((ext_vector_type(4)));

#define E_TOTAL 2000000
#define MT 128
#define NTILES (E_TOTAL / MT)   // 15625 exactly

// per-wave g tile pitch (ushorts): 64 cols + 8 pad -> row stride 144B = 36 dwords
// (= 4 mod 32 banks) -> 2-way aliasing on b128 reads (free, m136). 144B = 9*16 keeps
// every row 16B-aligned for ds_read_b128.
#define GP 72

__device__ __forceinline__ unsigned short f2bf(float x) {
  __hip_bfloat16 h = __float2bfloat16(x);
  return __builtin_bit_cast(unsigned short, h);
}

// Pre-kernel: bf16 weights into workspace.
// W1g[n*128+k] = bf16(W1[k][n])               (transposed, 64x128)
// B2g[n*64+k]  = bf16(B2[k][n])               (transposed, 80x64)
//   where B2[k][n] = W2[k][n] for n<64, (W2@Wp)[k][n-64] for 64<=n<69, else 0
__global__ void prep_kernel(const float* __restrict__ W1, const float* __restrict__ W2,
                            const float* __restrict__ Wp,
                            unsigned short* __restrict__ W1g,
                            unsigned short* __restrict__ B2g) {
  int t = blockIdx.x * blockDim.x + threadIdx.x;
  int stride = gridDim.x * blockDim.x;
  for (int i = t; i < 64 * 128; i += stride) {
    int n = i >> 7, k = i & 127;
    W1g[i] = f2bf(W1[k * 64 + n]);
  }
  for (int i = t; i < 80 * 64; i += stride) {
    int n = i >> 6, k = i & 63;
    float v;
    if (n < 64) {
      v = W2[k * 64 + n];
    } else if (n < 69) {
      int c = n - 64;
      float s = 0.f;
      for (int j = 0; j < 64; ++j) s += W2[k * 64 + j] * Wp[j * 5 + c];
      v = s;
    } else {
      v = 0.f;
    }
    B2g[i] = f2bf(v);
  }
}

__global__ __launch_bounds__(256, 6)
void mlp_main(const float* __restrict__ ufeat, const float* __restrict__ ifeat,
              const int* __restrict__ src, const int* __restrict__ dst,
              const unsigned short* __restrict__ W1g, const unsigned short* __restrict__ B2g,
              float* __restrict__ out) {
  // per-wave GELU-output tile (no cross-wave sharing): 4 waves x 32 rows x GP
  __shared__ __align__(16) unsigned short Gb[4 * 32 * GP];   // 18432 B -> LDS allows 8 blocks/CU

  const int lid  = threadIdx.x;
  const int lane = lid & 63;
  const int w    = lid >> 6;          // wave 0..3
  const int lr   = lane & 15;         // row/col within 16-tile
  const int q    = lane >> 4;         // lane quadrant 0..3
  const int lk   = q << 3;            // k offset 0,8,16,24
  const int tbase = blockIdx.x * MT;

  // ---- A-fragment gather setup: lane (lr,q) feeds rows e0,e0+16 with
  // 8 contiguous floats of u (q<2) or v (q>=2), chunk half (q&1). ----
  const int  e0  = tbase + w * 32 + lr;
  const bool isU = (q < 2);
  const int  i0  = isU ? src[e0] : dst[e0];
  const int  i1  = isU ? src[e0 + 16] : dst[e0 + 16];
  const float* tab = isU ? ufeat : ifeat;
  const float* r0 = tab + (size_t)i0 * 64 + ((q & 1) << 3);
  const float* r1 = tab + (size_t)i1 * 64 + ((q & 1) << 3);

  // ---- GEMM1: C1[128x64] = X[128x128] @ W1 ; A direct from global, B JIT (L1-resident) ----
  const f32x4 fz = {0.f, 0.f, 0.f, 0.f};
  f32x4 acc1[2][4];
  #pragma unroll
  for (int mi = 0; mi < 2; ++mi)
    #pragma unroll
    for (int nt = 0; nt < 4; ++nt) acc1[mi][nt] = fz;

  #pragma unroll
  for (int kk = 0; kk < 4; ++kk) {
    float4 f00 = *reinterpret_cast<const float4*>(r0 + 16 * kk);
    float4 f01 = *reinterpret_cast<const float4*>(r0 + 16 * kk + 4);
    float4 f10 = *reinterpret_cast<const float4*>(r1 + 16 * kk);
    float4 f11 = *reinterpret_cast<const float4*>(r1 + 16 * kk + 4);
    bf16x8 a0, a1;
    a0[0] = (short)f2bf(f00.x); a0[1] = (short)f2bf(f00.y);
    a0[2] = (short)f2bf(f00.z); a0[3] = (short)f2bf(f00.w);
    a0[4] = (short)f2bf(f01.x); a0[5] = (short)f2bf(f01.y);
    a0[6] = (short)f2bf(f01.z); a0[7] = (short)f2bf(f01.w);
    a1[0] = (short)f2bf(f10.x); a1[1] = (short)f2bf(f10.y);
    a1[2] = (short)f2bf(f10.z); a1[3] = (short)f2bf(f10.w);
    a1[4] = (short)f2bf(f11.x); a1[5] = (short)f2bf(f11.y);
    a1[6] = (short)f2bf(f11.z); a1[7] = (short)f2bf(f11.w);
    #pragma unroll
    for (int nt = 0; nt < 4; ++nt) {
      bf16x8 b = *reinterpret_cast<const bf16x8*>(&W1g[(nt * 16 + lr) * 128 + kk * 32 + lk]);
      acc1[0][nt] = __builtin_amdgcn_mfma_f32_16x16x32_bf16(a0, b, acc1[0][nt], 0, 0, 0);
      acc1[1][nt] = __builtin_amdgcn_mfma_f32_16x16x32_bf16(a1, b, acc1[1][nt], 0, 0, 0);
    }
  }

  // ---- exact GELU, write g (bf16) into this wave's LDS tile ----
  // C-layout: lane holds col=nt*16+lr, local row = 16*mi + 4*q + r
  unsigned short* gw = Gb + w * 32 * GP;
  #pragma unroll
  for (int mi = 0; mi < 2; ++mi) {
    #pragma unroll
    for (int nt = 0; nt < 4; ++nt) {
      f32x4 v = acc1[mi][nt];
      #pragma unroll
      for (int r = 0; r < 4; ++r) {
        float x  = v[r];
        float ge = 0.5f * x * (1.0f + erff(x * 0.70710678118654752f));
        gw[(16 * mi + 4 * q + r) * GP + nt * 16 + lr] = f2bf(ge);
      }
    }
  }
  __syncthreads();   // cross-lane visibility of g within the wave's tile

  // ---- GEMM2: C2[128x80] = g[128x64] @ [W2 | W2@Wp | 0] ; A from LDS, B JIT ----
  f32x4 acc2[2][5];
  #pragma unroll
  for (int mi = 0; mi < 2; ++mi)
    #pragma unroll
    for (int nt = 0; nt < 5; ++nt) acc2[mi][nt] = fz;

  #pragma unroll
  for (int kk = 0; kk < 2; ++kk) {
    int ko = kk * 32 + lk;
    bf16x8 a0 = *reinterpret_cast<const bf16x8*>(&gw[lr * GP + ko]);
    bf16x8 a1 = *reinterpret_cast<const bf16x8*>(&gw[(lr + 16) * GP + ko]);
    #pragma unroll
    for (int nt = 0; nt < 5; ++nt) {
      bf16x8 b = *reinterpret_cast<const bf16x8*>(&B2g[(nt * 16 + lr) * 64 + ko]);
      acc2[0][nt] = __builtin_amdgcn_mfma_f32_16x16x32_bf16(a0, b, acc2[0][nt], 0, 0, 0);
      acc2[1][nt] = __builtin_amdgcn_mfma_f32_16x16x32_bf16(a1, b, acc2[1][nt], 0, 0, 0);
    }
  }

  // ---- epilogue: h_fea = cols 0..63, score = cols 64..68 (nontemporal streaming) ----
  float* out_score = out;                 // [E,5]
  float* out_h     = out + 10000000;      // [E,64]
  #pragma unroll
  for (int mi = 0; mi < 2; ++mi) {
    int er0 = tbase + (2 * w + mi) * 16 + 4 * q;
    #pragma unroll
    for (int nt = 0; nt < 4; ++nt) {
      #pragma unroll
      for (int r = 0; r < 4; ++r)
        __builtin_nontemporal_store(acc2[mi][nt][r],
                                    &out_h[(size_t)(er0 + r) * 64 + nt * 16 + lr]);
    }
    if (lr < 5) {
      #pragma unroll
      for (int r = 0; r < 4; ++r)
        __builtin_nontemporal_store(acc2[mi][4][r],
                                    &out_score[(size_t)(er0 + r) * 5 + lr]);
    }
  }
}

extern "C" void kernel_launch(void* const* d_in, const int* in_sizes, int n_in,
                              void* d_out, int out_size, void* d_ws, size_t ws_size,
                              hipStream_t stream) {
  const float* ufeat = (const float*)d_in[0];
  const float* ifeat = (const float*)d_in[1];
  const float* W1    = (const float*)d_in[2];
  const float* W2    = (const float*)d_in[3];
  const float* Wp    = (const float*)d_in[4];
  const int*   src   = (const int*)d_in[5];
  const int*   dst   = (const int*)d_in[6];

  unsigned short* W1g = (unsigned short*)d_ws;            // 8192 ushorts
  unsigned short* B2g = W1g + 64 * 128;                   // 5120 ushorts

  prep_kernel<<<16, 256, 0, stream>>>(W1, W2, Wp, W1g, B2g);
  mlp_main<<<NTILES, 256, 0, stream>>>(ufeat, ifeat, src, dst, W1g, B2g, (float*)d_out);
}